// Round 4
// baseline (1918.900 us; speedup 1.0000x reference)
//
#include <hip/hip_runtime.h>
#include <hip/hip_bf16.h>
#include <cfloat>

#define B_ 2
#define S_ 2048
#define D_ 2048
#define H_ 16
#define KV_ 4
#define HD_ 128
#define R_ 4
#define MLP_ 8192
#define N_ (B_*S_)

typedef unsigned short ushort_t;
typedef __bf16 bf16x8 __attribute__((ext_vector_type(8)));
typedef float f32x4 __attribute__((ext_vector_type(4)));

__device__ __forceinline__ float b2f(ushort_t u) {
    unsigned x = ((unsigned)u) << 16;
    return __builtin_bit_cast(float, x);
}
__device__ __forceinline__ ushort_t f2b(float f) {
    unsigned u = __builtin_bit_cast(unsigned, f);
    unsigned r = (u + 0x7fffu + ((u >> 16) & 1u)) >> 16;   // RNE
    return (ushort_t)r;
}

__device__ __forceinline__ void gload_lds16(const void* g, void* l) {
    __builtin_amdgcn_global_load_lds(
        (__attribute__((address_space(1))) void*)(g),
        (__attribute__((address_space(3))) void*)(l), 16, 0, 0);
}

// XCD-aware swizzle: blocks with flat%8 == c (same XCD under round-robin) get a
// contiguous logical range; column-major decompose so an XCD's blocks share a
// narrow W-block set (fits 4MB L2) while sweeping token rows.
__device__ __forceinline__ void xcd_swizzle(int& bx, int& by) {
    int gx = gridDim.x, gy = gridDim.y;
    int flat = blockIdx.y * gx + blockIdx.x;
    int G = gx * gy;
    int n = (flat & 7) * (G >> 3) + (flat >> 3);
    bx = n / gy;
    by = n % gy;
}

// ---------------- fp32 -> bf16 conversion ----------------
__global__ __launch_bounds__(256) void f2bf_kernel(const float* __restrict__ in,
                                                   ushort_t* __restrict__ out, int n4)
{
    int i = blockIdx.x * 256 + threadIdx.x;
    if (i < n4) {
        float4 v = ((const float4*)in)[i];
        ushort4 o;
        o.x = f2b(v.x); o.y = f2b(v.y); o.z = f2b(v.z); o.w = f2b(v.w);
        ((ushort4*)out)[i] = o;
    }
}

// ---------------- mix + RMS -> bf16 h (optionally fp32 xm) ----------------
template<bool MIX>
__global__ __launch_bounds__(256) void rms_kernel(
    const float* __restrict__ x, const float* __restrict__ x0,
    const float* __restrict__ rm, float* __restrict__ xm_out,
    ushort_t* __restrict__ h_out)
{
    int n = blockIdx.x;
    int tid = threadIdx.x;
    const float4* xr = (const float4*)(x + (size_t)n * D_);
    float4 v[2];
    float ss = 0.f;
#pragma unroll
    for (int i = 0; i < 2; i++) {
        int c = tid + i * 256;
        float4 a = xr[c];
        if (MIX) {
            const float4* x0r = (const float4*)(x0 + (size_t)n * D_);
            const float4* rma = (const float4*)rm;
            const float4* rmb = (const float4*)(rm + D_);
            float4 b = x0r[c];
            float4 ra = rma[c], rb = rmb[c];
            a.x = ra.x*a.x + rb.x*b.x;
            a.y = ra.y*a.y + rb.y*b.y;
            a.z = ra.z*a.z + rb.z*b.z;
            a.w = ra.w*a.w + rb.w*b.w;
            ((float4*)(xm_out + (size_t)n * D_))[c] = a;
        }
        v[i] = a;
        ss += a.x*a.x + a.y*a.y + a.z*a.z + a.w*a.w;
    }
#pragma unroll
    for (int off = 32; off; off >>= 1) ss += __shfl_xor(ss, off);
    __shared__ float red[4];
    if ((tid & 63) == 0) red[tid >> 6] = ss;
    __syncthreads();
    float tot = red[0] + red[1] + red[2] + red[3];
    float r = rsqrtf(tot * (1.f / (float)D_) + FLT_EPSILON);
    ushort4* ho = (ushort4*)(h_out + (size_t)n * D_);
#pragma unroll
    for (int i = 0; i < 2; i++) {
        int c = tid + i * 256;
        float4 a = v[i];
        ushort4 o;
        o.x = f2b(a.x * r); o.y = f2b(a.y * r); o.z = f2b(a.z * r); o.w = f2b(a.w * r);
        ho[c] = o;
    }
}

// ---------------- bf16 MFMA GEMM: C[n,m] = sum_k A[n,k]*W[m,k] ----------------
template<int EPI, typename OutT>
__global__ __launch_bounds__(256) void gemm_bf16(
    const ushort_t* __restrict__ A, const ushort_t* __restrict__ W,
    OutT* __restrict__ C, int M, int Kd,
    const float* __restrict__ src, const float* __restrict__ svec)
{
    __shared__ ushort_t As[128 * 32];
    __shared__ ushort_t Bs[128 * 32];
    const int tid = threadIdx.x;
    const int wid = tid >> 6, lane = tid & 63;
    int bxs, bys;
    xcd_swizzle(bxs, bys);
    const int bn = bys * 128;      // token rows
    const int bm = bxs * 128;      // feature cols
    const int wn = (wid >> 1) * 64;
    const int wm = (wid & 1) * 64;

    f32x4 acc[4][4] = {};

    const int lr = lane & 15;
    const int lk = (lane >> 4) * 16;      // byte offset
    const char* Ab = (const char*)As;
    const char* Bb = (const char*)Bs;
    const int ub0 = wid * 128;

#pragma unroll
    for (int p = 0; p < 2; p++) {
        int ub = ub0 + p * 64;
        int u = ub + lane;
        gload_lds16(A + (size_t)(bn + (u >> 2)) * Kd + (u & 3) * 8, (char*)As + ub * 16);
        gload_lds16(W + (size_t)(bm + (u >> 2)) * Kd + (u & 3) * 8, (char*)Bs + ub * 16);
    }
    __syncthreads();

    for (int k0 = 0;;) {
        bf16x8 af[4], bfr[4];
#pragma unroll
        for (int i = 0; i < 4; i++)
            af[i] = *(const bf16x8*)(Ab + (wn + i * 16 + lr) * 64 + lk);
#pragma unroll
        for (int j = 0; j < 4; j++)
            bfr[j] = *(const bf16x8*)(Bb + (wm + j * 16 + lr) * 64 + lk);
#pragma unroll
        for (int i = 0; i < 4; i++)
#pragma unroll
            for (int j = 0; j < 4; j++)
                acc[i][j] = __builtin_amdgcn_mfma_f32_16x16x32_bf16(af[i], bfr[j], acc[i][j], 0, 0, 0);

        k0 += 32;
        if (k0 >= Kd) break;
        __syncthreads();
#pragma unroll
        for (int p = 0; p < 2; p++) {
            int ub = ub0 + p * 64;
            int u = ub + lane;
            gload_lds16(A + (size_t)(bn + (u >> 2)) * Kd + k0 + (u & 3) * 8, (char*)As + ub * 16);
            gload_lds16(W + (size_t)(bm + (u >> 2)) * Kd + k0 + (u & 3) * 8, (char*)Bs + ub * 16);
        }
        __syncthreads();
    }

    const int cr = (lane >> 4) * 4;
    const int ccol = lane & 15;
#pragma unroll
    for (int i = 0; i < 4; i++) {
#pragma unroll
        for (int r = 0; r < 4; r++) {
            size_t rowoff = (size_t)(bn + wn + i * 16 + cr + r) * M;
#pragma unroll
            for (int j = 0; j < 4; j++) {
                int m = bm + wm + j * 16 + ccol;
                size_t off = rowoff + m;
                float v = acc[i][j][r];
                if (EPI == 1) v += src[off];
                else if (EPI == 2) v = src[off] + svec[m] * v;
                else if (EPI == 3) { float t = v >= 0.f ? v : 0.5f * v; v = t * t; }
                if constexpr (sizeof(OutT) == 2) C[off] = (OutT)f2b(v);
                else                             C[off] = v;
            }
        }
    }
}

// ---------------- fused QKV GEMM ----------------
// W = [q_w | k_w | v_w] rows (3072 x 2048). Epilogue:
//   q cols (bm<2048):      per-head RMS + RoPE + q_gain -> qb (bf16)
//   k cols (2048..2560):   per-head RMS + RoPE          -> kb (bf16)
//   v cols (>=2560):       +v_embed -> out_vr (fp32), lambda-mix v0 -> vmb, vtb
__global__ __launch_bounds__(256) void gemm_qkv(
    const ushort_t* __restrict__ A, const ushort_t* __restrict__ W,
    ushort_t* __restrict__ qb, ushort_t* __restrict__ kb,
    float* __restrict__ out_vr, ushort_t* __restrict__ vmb, ushort_t* __restrict__ vtb,
    const float* __restrict__ v_embed, const float* __restrict__ v0,
    const float* __restrict__ q_gain, const float* __restrict__ vr_lambda)
{
    __shared__ ushort_t As[128 * 32];
    __shared__ ushort_t Bs[128 * 32];
    __shared__ float ssb[2][128];
    __shared__ ushort_t xb[128][132];   // padded: breaks pow-2 bank stride
    const int tid = threadIdx.x;
    const int wid = tid >> 6, lane = tid & 63;
    int bxs, bys;
    xcd_swizzle(bxs, bys);
    const int bn = bys * 128;
    const int bm = bxs * 128;
    const int wn = (wid >> 1) * 64;
    const int wm = (wid & 1) * 64;
    const int l15 = lane & 15, quad = lane >> 4;
    const int Kd = D_;

    f32x4 acc[4][4] = {};
    const int lr = lane & 15;
    const int lk = (lane >> 4) * 16;
    const char* Ab = (const char*)As;
    const char* Bb = (const char*)Bs;
    const int ub0 = wid * 128;

#pragma unroll
    for (int p = 0; p < 2; p++) {
        int ub = ub0 + p * 64;
        int u = ub + lane;
        gload_lds16(A + (size_t)(bn + (u >> 2)) * Kd + (u & 3) * 8, (char*)As + ub * 16);
        gload_lds16(W + (size_t)(bm + (u >> 2)) * Kd + (u & 3) * 8, (char*)Bs + ub * 16);
    }
    __syncthreads();

    for (int k0 = 0;;) {
        bf16x8 af[4], bfr[4];
#pragma unroll
        for (int i = 0; i < 4; i++)
            af[i] = *(const bf16x8*)(Ab + (wn + i * 16 + lr) * 64 + lk);
#pragma unroll
        for (int j = 0; j < 4; j++)
            bfr[j] = *(const bf16x8*)(Bb + (wm + j * 16 + lr) * 64 + lk);
#pragma unroll
        for (int i = 0; i < 4; i++)
#pragma unroll
            for (int j = 0; j < 4; j++)
                acc[i][j] = __builtin_amdgcn_mfma_f32_16x16x32_bf16(af[i], bfr[j], acc[i][j], 0, 0, 0);
        k0 += 32;
        if (k0 >= Kd) break;
        __syncthreads();
#pragma unroll
        for (int p = 0; p < 2; p++) {
            int ub = ub0 + p * 64;
            int u = ub + lane;
            gload_lds16(A + (size_t)(bn + (u >> 2)) * Kd + k0 + (u & 3) * 8, (char*)As + ub * 16);
            gload_lds16(W + (size_t)(bm + (u >> 2)) * Kd + k0 + (u & 3) * 8, (char*)Bs + ub * 16);
        }
        __syncthreads();
    }

    if (bm >= 2560) {
        // ---- v branch ----
        const int kv = (bm - 2560) >> 7;
        const float l0 = vr_lambda[0], l1 = vr_lambda[1];
#pragma unroll
        for (int i = 0; i < 4; i++) {
#pragma unroll
            for (int r = 0; r < 4; r++) {
                int row = wn + i * 16 + quad * 4 + r;
                int n = bn + row;
                int bidx = n >> 11, s = n & (S_ - 1);
#pragma unroll
                for (int j = 0; j < 4; j++) {
                    int c512 = kv * HD_ + wm + j * 16 + l15;
                    size_t off = (size_t)n * (KV_*HD_) + c512;
                    float vr = acc[i][j][r] + v_embed[off];
                    out_vr[off] = vr;
                    float vm = l0 * v0[off] + l1 * vr;
                    ushort_t vmh = f2b(vm);
                    vmb[off] = vmh;
                    vtb[((size_t)(bidx * (KV_*HD_) + c512)) * S_ + s] = vmh;
                }
            }
        }
        return;
    }

    // ---- q/k branch: per-head RMS + RoPE ----
    const bool isq = (bm < 2048);
    const int head = bm >> 7;              // q head (valid when isq)
    const float gain = isq ? q_gain[head] : 1.f;

    // 1) row sum-of-squares over this wave's 64 cols
    f32x4 rms4[4];
#pragma unroll
    for (int i = 0; i < 4; i++) {
        f32x4 sv = {0.f, 0.f, 0.f, 0.f};
#pragma unroll
        for (int j = 0; j < 4; j++)
#pragma unroll
            for (int r = 0; r < 4; r++) sv[r] += acc[i][j][r] * acc[i][j][r];
#pragma unroll
        for (int r = 0; r < 4; r++) {
            float ss = sv[r];
#pragma unroll
            for (int o = 1; o < 16; o <<= 1) ss += __shfl_xor(ss, o);
            if (l15 == 0) ssb[wid & 1][wn + i * 16 + quad * 4 + r] = ss;
            sv[r] = ss;  // keep for later (partial)
        }
        rms4[i] = sv;
    }
    __syncthreads();
    // 2) combine halves, normalize, stage to LDS for the cross-half exchange
#pragma unroll
    for (int i = 0; i < 4; i++) {
#pragma unroll
        for (int r = 0; r < 4; r++) {
            int row = wn + i * 16 + quad * 4 + r;
            float tot = ssb[0][row] + ssb[1][row];
            rms4[i][r] = rsqrtf(tot * (1.f / (float)HD_) + FLT_EPSILON);
        }
#pragma unroll
        for (int j = 0; j < 4; j++)
#pragma unroll
            for (int r = 0; r < 4; r++) {
                int row = wn + i * 16 + quad * 4 + r;
                xb[row][wm + j * 16 + l15] = f2b(acc[i][j][r] * rms4[i][r]);
            }
    }
    __syncthreads();
    // 3) RoPE + store
    const float L2B = 14.303585395422465f;  // log2(10000 * 2^(128/126))
    ushort_t* dst = isq ? qb : kb;
    const int dstride = isq ? D_ : (KV_*HD_);
    const int dbase = isq ? bm : (bm - 2048);
#pragma unroll
    for (int j = 0; j < 4; j++) {
        int dcol = wm + j * 16 + l15;
        float invf = exp2f(-(float)(dcol & 63) * (L2B / 64.f));
#pragma unroll
        for (int i = 0; i < 4; i++) {
#pragma unroll
            for (int r = 0; r < 4; r++) {
                int row = wn + i * 16 + quad * 4 + r;
                int n = bn + row;
                int s = n & (S_ - 1);
                float fr = (float)s * invf;
                float c = cosf(fr), sn = sinf(fr);
                float xs = acc[i][j][r] * rms4[i][r];
                float xp = b2f(xb[row][dcol ^ 64]);
                float outv = (wm == 0) ? (xs * c + xp * sn) : (xs * c - xp * sn);
                dst[(size_t)n * dstride + dbase + dcol] = f2b(outv * gain);
            }
        }
    }
}

// ---------------- MFMA flash attention (bf16 in/out, fp32 softmax/accum) ----------------
__global__ __launch_bounds__(256) void attn_mfma_kernel(
    const ushort_t* __restrict__ Qg, const ushort_t* __restrict__ Kg,
    const ushort_t* __restrict__ Vtg, ushort_t* __restrict__ Y)
{
    const int b = blockIdx.z, h = blockIdx.y;
    const int kv = h >> 2;
    const int bx = gridDim.x - 1 - blockIdx.x;   // heavy (long-K) blocks first
    const int qrow0 = bx * 64;
    const int tid = threadIdx.x;
    const int wid = tid >> 6, lane = tid & 63;
    const int l15 = lane & 15, quad = lane >> 4;

    __shared__ ushort_t Ks[4 * 64 * 32];     // 16 KB
    __shared__ ushort_t Vs[2 * 128 * 32];    // 16 KB
    __shared__ ushort_t Ps[4][2 * 16 * 32];  // 8 KB (per-wave private)

    bf16x8 qf[4];
    {
        const ushort_t* qrow = Qg + (size_t)(b * S_ + qrow0 + wid * 16 + l15) * D_ + h * HD_ + quad * 8;
#pragma unroll
        for (int kc = 0; kc < 4; kc++)
            qf[kc] = __builtin_bit_cast(bf16x8, *(const uint4*)(qrow + kc * 32));
    }

    f32x4 O[8];
    float m_r[4], l_r[4];
#pragma unroll
    for (int dt = 0; dt < 8; dt++)
#pragma unroll
        for (int r = 0; r < 4; r++) O[dt][r] = 0.f;
#pragma unroll
    for (int r = 0; r < 4; r++) { m_r[r] = -1e30f; l_r[r] = 0.f; }

    const size_t kgbase = (size_t)b * S_ * (KV_*HD_) + kv * HD_;
    const size_t vgbase = (size_t)(b * KV_ + kv) * HD_ * S_;
    const float CS = 0.12751743f;  // 1/sqrt(128) * log2(e)

    const int ntiles = bx + 1;
    for (int t = 0; t < ntiles; t++) {
        const int k0 = t * 64;
        if (t) __syncthreads();
#pragma unroll
        for (int p = 0; p < 4; p++) {
            int ub = wid * 256 + p * 64 + lane;
            int kc = ub >> 8, j = (ub >> 2) & 63, q = ub & 3;
            gload_lds16(Kg + kgbase + (size_t)(k0 + j) * (KV_*HD_) + kc * 32 + q * 8,
                        (char*)Ks + ub * 16);
            int jc = ub >> 9, d = (ub >> 2) & 127;
            gload_lds16(Vtg + vgbase + (size_t)d * S_ + k0 + jc * 32 + q * 8,
                        (char*)Vs + ub * 16);
        }
        __syncthreads();

        f32x4 sc[4];
#pragma unroll
        for (int jt = 0; jt < 4; jt++)
#pragma unroll
            for (int r = 0; r < 4; r++) sc[jt][r] = 0.f;
#pragma unroll
        for (int kc = 0; kc < 4; kc++) {
#pragma unroll
            for (int jt = 0; jt < 4; jt++) {
                bf16x8 kf = *(const bf16x8*)(Ks + kc * 2048 + (jt * 16 + l15) * 32 + quad * 8);
                sc[jt] = __builtin_amdgcn_mfma_f32_16x16x32_bf16(qf[kc], kf, sc[jt], 0, 0, 0);
            }
        }

        float pv[4][4];
        const bool diag = (t == ntiles - 1);
#pragma unroll
        for (int jt = 0; jt < 4; jt++)
#pragma unroll
            for (int r = 0; r < 4; r++) {
                float s = sc[jt][r] * CS;
                if (diag && (jt * 16 + l15 > wid * 16 + quad * 4 + r)) s = -1e30f;
                pv[jt][r] = s;
            }
        float al[4];
#pragma unroll
        for (int r = 0; r < 4; r++) {
            float m0 = fmaxf(fmaxf(pv[0][r], pv[1][r]), fmaxf(pv[2][r], pv[3][r]));
#pragma unroll
            for (int o = 1; o < 16; o <<= 1) m0 = fmaxf(m0, __shfl_xor(m0, o));
            float mn = fmaxf(m_r[r], m0);
            al[r] = exp2f(m_r[r] - mn);
            m_r[r] = mn;
            float srow = 0.f;
#pragma unroll
            for (int jt = 0; jt < 4; jt++) { pv[jt][r] = exp2f(pv[jt][r] - mn); srow += pv[jt][r]; }
#pragma unroll
            for (int o = 1; o < 16; o <<= 1) srow += __shfl_xor(srow, o);
            l_r[r] = l_r[r] * al[r] + srow;
        }
#pragma unroll
        for (int dt = 0; dt < 8; dt++)
#pragma unroll
            for (int r = 0; r < 4; r++) O[dt][r] *= al[r];

        ushort_t* pw = Ps[wid];
#pragma unroll
        for (int jt = 0; jt < 4; jt++)
#pragma unroll
            for (int r = 0; r < 4; r++)
                pw[(jt >> 1) * 512 + (quad * 4 + r) * 32 + (jt & 1) * 16 + l15] = f2b(pv[jt][r]);

#pragma unroll
        for (int jc = 0; jc < 2; jc++) {
            bf16x8 pf = *(const bf16x8*)(pw + jc * 512 + l15 * 32 + quad * 8);
#pragma unroll
            for (int dt = 0; dt < 8; dt++) {
                bf16x8 vf = *(const bf16x8*)(Vs + jc * 4096 + (dt * 16 + l15) * 32 + quad * 8);
                O[dt] = __builtin_amdgcn_mfma_f32_16x16x32_bf16(pf, vf, O[dt], 0, 0, 0);
            }
        }
    }

#pragma unroll
    for (int r = 0; r < 4; r++) {
        float inv = 1.f / l_r[r];
        size_t row = (size_t)(b * S_ + qrow0 + wid * 16 + quad * 4 + r) * D_ + h * HD_;
#pragma unroll
        for (int dt = 0; dt < 8; dt++)
            Y[row + dt * 16 + l15] = f2b(O[dt][r] * inv);
    }
}

// ---------------- v-hat projection + sigmoid gate (bf16 y in-place) ----------------
__global__ __launch_bounds__(256) void postproc_kernel(
    const ushort_t* __restrict__ h, const ushort_t* __restrict__ vmix,
    const float* __restrict__ gw, const float* __restrict__ gb,
    ushort_t* __restrict__ y)
{
    int n = blockIdx.x;
    int tid = threadIdx.x;
    int wave = tid >> 6, lane = tid & 63;
    const ushort_t* hrow = h + (size_t)n * D_;
    float acc[4] = {0.f, 0.f, 0.f, 0.f};
    for (int d = lane; d < D_; d += 64) {
        float hv = b2f(hrow[d]);
#pragma unroll
        for (int r = 0; r < 4; r++)
            acc[r] += hv * gw[(size_t)(wave*4 + r) * D_ + d];
    }
#pragma unroll
    for (int off = 32; off; off >>= 1)
#pragma unroll
        for (int r = 0; r < 4; r++) acc[r] += __shfl_xor(acc[r], off);
    float gate[4];
#pragma unroll
    for (int r = 0; r < 4; r++)
        gate[r] = 1.f / (1.f + __expf(-(acc[r] + gb[wave*4 + r])));
    const ushort_t* vrow = vmix + (size_t)n * (KV_*HD_) + wave * HD_;
    float v0 = b2f(vrow[lane]), v1 = b2f(vrow[lane + 64]);
    float ss = v0*v0 + v1*v1;
#pragma unroll
    for (int off = 32; off; off >>= 1) ss += __shfl_xor(ss, off);
    float nrm = fmaxf(sqrtf(ss), 1e-12f);
    float vh0 = v0 / nrm, vh1 = v1 / nrm;
    ushort_t* yrow = y + (size_t)n * D_ + wave * (R_ * HD_);
#pragma unroll
    for (int r = 0; r < 4; r++) {
        float y0 = b2f(yrow[r*HD_ + lane]), y1 = b2f(yrow[r*HD_ + lane + 64]);
        float dot = y0*vh0 + y1*vh1;
#pragma unroll
        for (int off = 32; off; off >>= 1) dot += __shfl_xor(dot, off);
        yrow[r*HD_ + lane]      = f2b((y0 - dot*vh0) * gate[r]);
        yrow[r*HD_ + lane + 64] = f2b((y1 - dot*vh1) * gate[r]);
    }
}

extern "C" void kernel_launch(void* const* d_in, const int* in_sizes, int n_in,
                              void* d_out, int out_size, void* d_ws, size_t ws_size,
                              hipStream_t stream) {
    const float* x          = (const float*)d_in[0];
    const float* x0         = (const float*)d_in[1];
    const float* q_w        = (const float*)d_in[2];
    const float* k_w        = (const float*)d_in[3];
    const float* v_w        = (const float*)d_in[4];
    const float* out_w      = (const float*)d_in[5];
    const float* up_w       = (const float*)d_in[6];
    const float* down_w     = (const float*)d_in[7];
    const float* v_embed    = (const float*)d_in[8];
    const float* v0         = (const float*)d_in[9];
    const float* q_gain     = (const float*)d_in[10];
    const float* gate_w     = (const float*)d_in[11];
    const float* gate_b     = (const float*)d_in[12];
    const float* vr_lambda  = (const float*)d_in[13];
    const float* attn_scale = (const float*)d_in[14];
    const float* mlp_scale  = (const float*)d_in[15];
    const float* resid_mix  = (const float*)d_in[16];

    float* out_c  = (float*)d_out;
    float* out_vr = out_c + (size_t)N_ * D_;

    // phase-aliased workspace (peak 151.0 MB, proven available)
    char* w = (char*)d_ws;
    ushort_t* hb  = (ushort_t*)(w + 0);            // 16.8MB
    float*    xm  = (float*)   (w + 16777216);     // 33.5MB
    ushort_t* qb  = (ushort_t*)(w + 50331648);     // 16.8MB
    ushort_t* kb  = (ushort_t*)(w + 67108864);     //  4.2MB
    ushort_t* vmb = (ushort_t*)(w + 71303168);     //  4.2MB
    ushort_t* yb  = (ushort_t*)(w + 75497472);     // 16.8MB
    ushort_t* wq  = (ushort_t*)(w + 92274688);     //  8.4MB  } contiguous 12.6MB
    ushort_t* wk  = (ushort_t*)(w + 100663296);    //  2.1MB  } = wcat [3072x2048]
    ushort_t* wv  = (ushort_t*)(w + 102760448);    //  2.1MB  }
    ushort_t* wo  = (ushort_t*)(w + 104857600);    //  8.4MB
    ushort_t* vtb = (ushort_t*)(w + 113246208);    //  4.2MB
    ushort_t* act = (ushort_t*)(w + 16777216);     // 67.1MB (aliases xm..yb, MLP phase)
    ushort_t* wu  = (ushort_t*)(w + 83886080);     // 33.5MB (aliases yb tail + wq..wo)
    ushort_t* wd  = (ushort_t*)(w + 117440512);    // 33.5MB, ends 150994944
    ushort_t* m2  = (ushort_t*)(w + 0);            // aliases hb (MLP phase)

    f2bf_kernel<<<4096, 256, 0, stream>>>(q_w,    wq, 2048*2048/4);
    f2bf_kernel<<<1024, 256, 0, stream>>>(k_w,    wk,  512*2048/4);
    f2bf_kernel<<<1024, 256, 0, stream>>>(v_w,    wv,  512*2048/4);
    f2bf_kernel<<<4096, 256, 0, stream>>>(out_w,  wo, 2048*2048/4);
    f2bf_kernel<<<16384,256, 0, stream>>>(down_w, wd, 2048*8192/4);

    // 1. xm = mix(x,x0) fp32; h = rms(xm) bf16
    rms_kernel<true><<<N_, 256, 0, stream>>>(x, x0, resid_mix, xm, hb);
    // 2-4. fused QKV projections + RMS/RoPE/gain + v_embed/lambda-mix/transpose
    gemm_qkv<<<dim3(24, 32), 256, 0, stream>>>(hb, wq, qb, kb, out_vr, vmb, vtb,
                                               v_embed, v0, q_gain, vr_lambda);
    // 5. causal GQA attention (MFMA flash) -> yb
    attn_mfma_kernel<<<dim3(S_/64, H_, B_), 256, 0, stream>>>(qb, kb, vtb, yb);
    // 6. v-hat projection + gate (in-place on yb)
    postproc_kernel<<<N_, 256, 0, stream>>>(hb, vmb, gate_w, gate_b, yb);
    // 7. c = xm + attn_scale * (yb @ out_w.T) -> out_c
    gemm_bf16<2, float><<<dim3(16, 32), 256, 0, stream>>>(yb, wo, out_c, D_, D_, xm, attn_scale);
    f2bf_kernel<<<16384, 256, 0, stream>>>(up_w, wu, 8192*2048/4);
    // 8. m2 = rms(c) bf16
    rms_kernel<false><<<N_, 256, 0, stream>>>(out_c, nullptr, nullptr, nullptr, m2);
    // 9. act = sqrelu(m2 @ up_w.T)
    gemm_bf16<3, ushort_t><<<dim3(64, 32), 256, 0, stream>>>(m2, wu, act, MLP_, D_, nullptr, nullptr);
    // 10. c += mlp_scale * (act @ down_w.T)
    gemm_bf16<2, float><<<dim3(16, 32), 256, 0, stream>>>(act, wd, out_c, D_, MLP_, out_c, mlp_scale);
}